// Round 1
// baseline (294.422 us; speedup 1.0000x reference)
//
#include <hip/hip_runtime.h>

// SelfAttention: B=8, S=2048, D_MODEL=1024, D_OUT=64, causal, single head.
// Plan:
//  k_wconv  : W[1024][64] f32 -> Wt[64][1024] bf16 (x3), so proj B-frags are contiguous.
//  k_proj   : X[16384][1024] f32 @ Wt -> Qp/Kp bf16 [16384][64]; V written transposed
//             Vt bf16 [8][64][2048] so PV B-frags are contiguous.
//  k_attn   : split-K flash attention. Tasks = (qtile, k-chunk<=512), partial chunks
//             paired (j,30-j) for uniform ~8-9 ktile work; 2080 wave-tasks total.
//             Writes unnormalized partial O + (m,l) per row to ws.
//  k_combine: merges up to 4 partials per qtile with m/l rescale -> f32 out.
// Causal mask hardcoded (input mask is analytically tril). Biases honored.

#define DM 1024
#define DO 64
#define SQ 2048

typedef __attribute__((ext_vector_type(4))) float f32x4;
typedef __attribute__((ext_vector_type(8))) short bf16x8;

__device__ __forceinline__ short f2bf(float x) {
  union { float f; unsigned u; } v; v.f = x;
  unsigned r = v.u + 0x7FFFu + ((v.u >> 16) & 1u);   // RNE
  return (short)(r >> 16);
}

// ---------------- W transpose+convert: Wt[m][c][k] = W_m[k][c] as bf16 ----------------
__global__ __launch_bounds__(256) void k_wconv(const float* __restrict__ Wq,
                                               const float* __restrict__ Wk,
                                               const float* __restrict__ Wv,
                                               short* __restrict__ Wt) {
  int id = blockIdx.x * 256 + threadIdx.x;           // 3*64*1024 = 196608
  int m = id >> 16;
  int rem = id & 65535;
  int cidx = rem >> 10;
  int kk = rem & 1023;
  const float* W = (m == 0) ? Wq : (m == 1) ? Wk : Wv;
  Wt[id] = f2bf(W[kk * DO + cidx]);                  // coalesced writes
}

// ---------------- Projections ----------------
// grid 768: bid>>8 = matrix (0=Q,1=K,2=V), bid&255 = 64-row tile. 4 waves, 16 rows each.
// barrier-free: A-frags straight from global f32 (cvt to bf16), B-frags from Wt (L2).
__global__ __launch_bounds__(256) void k_proj(const float* __restrict__ q,
                                              const float* __restrict__ k,
                                              const float* __restrict__ v,
                                              const float* __restrict__ bq,
                                              const float* __restrict__ bk,
                                              const float* __restrict__ bv,
                                              const short* __restrict__ Wt,
                                              short* __restrict__ Qp,
                                              short* __restrict__ Kp,
                                              short* __restrict__ Vt) {
  int bid = blockIdx.x;
  int m = bid >> 8, mt = bid & 255;
  const float* X    = (m == 0) ? q  : (m == 1) ? k  : v;
  const float* bias = (m == 0) ? bq : (m == 1) ? bk : bv;
  const short* W = Wt + (m << 16);
  int tid = threadIdx.x;
  int w = tid >> 6, lane = tid & 63, g = lane >> 4, c = lane & 15;
  const float* Xrow = X + (size_t)(mt * 64 + 16 * w + c) * DM;
  f32x4 acc[4] = {{0,0,0,0},{0,0,0,0},{0,0,0,0},{0,0,0,0}};
#pragma unroll 4
  for (int k0 = 0; k0 < DM; k0 += 32) {
    const float* xp = Xrow + k0 + 8 * g;
    f32x4 xa = *(const f32x4*)xp;
    f32x4 xb = *(const f32x4*)(xp + 4);
    bf16x8 af;
    af[0] = f2bf(xa[0]); af[1] = f2bf(xa[1]); af[2] = f2bf(xa[2]); af[3] = f2bf(xa[3]);
    af[4] = f2bf(xb[0]); af[5] = f2bf(xb[1]); af[6] = f2bf(xb[2]); af[7] = f2bf(xb[3]);
#pragma unroll
    for (int ct = 0; ct < 4; ++ct) {
      bf16x8 bfr = *(const bf16x8*)(W + (16 * ct + c) * DM + k0 + 8 * g);
      acc[ct] = __builtin_amdgcn_mfma_f32_16x16x32_bf16(af, bfr, acc[ct], 0, 0, 0);
    }
  }
  int row0 = mt * 64 + 16 * w;                       // C rows are row0 + 4g + r
  if (m < 2) {
    short* dst = (m == 0) ? Qp : Kp;
#pragma unroll
    for (int ct = 0; ct < 4; ++ct) {
      float bb = bias[16 * ct + c];
#pragma unroll
      for (int r = 0; r < 4; ++r)
        dst[(size_t)(row0 + 4 * g + r) * DO + 16 * ct + c] = f2bf(acc[ct][r] + bb);
    }
  } else {
    // Vt[batch][d][s]: d = 16ct+c, s = row0+4g+r (4 consecutive s -> one 8B store)
    int batch = row0 >> 11, sl = row0 & 2047;
#pragma unroll
    for (int ct = 0; ct < 4; ++ct) {
      float bb = bias[16 * ct + c];
      ushort4 pk;
      pk.x = (unsigned short)f2bf(acc[ct][0] + bb);
      pk.y = (unsigned short)f2bf(acc[ct][1] + bb);
      pk.z = (unsigned short)f2bf(acc[ct][2] + bb);
      pk.w = (unsigned short)f2bf(acc[ct][3] + bb);
      *(ushort4*)(Vt + (size_t)(batch * 64 + 16 * ct + c) * SQ + sl + 4 * g) = pk;
    }
  }
}

// ---------------- Flash attention (split-K, partials) ----------------
// One wave = one task: qtile t (16 rows), k in [k0, kend). Writes unnormalized
// partial O[16][64] + (m,l)[16] at slot `slot` of qtile t.
__device__ __forceinline__ void attn_task(int batch, int t, int k0, int kend, int slot,
                                          int g, int c, short (*P)[72],
                                          const short* __restrict__ Qp,
                                          const short* __restrict__ Kp,
                                          const short* __restrict__ Vt,
                                          float* __restrict__ Po,
                                          float* __restrict__ Pml) {
  const int qb = t * 16;
  const short* Qrow = Qp + (size_t)((batch << 11) + qb + c) * DO;
  bf16x8 qf0 = *(const bf16x8*)(Qrow + 8 * g);
  bf16x8 qf1 = *(const bf16x8*)(Qrow + 32 + 8 * g);
  f32x4 acc[4] = {{0,0,0,0},{0,0,0,0},{0,0,0,0},{0,0,0,0}};
  float mr[4] = {-1e30f, -1e30f, -1e30f, -1e30f};
  float lr[4] = {0.f, 0.f, 0.f, 0.f};
  int nkt = (kend - k0 + 63) >> 6;
  for (int kt = 0; kt < nkt; ++kt) {
    int kk = k0 + (kt << 6);
    // QK^T: S[4g+r][16ct+c]
    f32x4 s[4];
#pragma unroll
    for (int ct = 0; ct < 4; ++ct) {
      const short* Krow = Kp + (size_t)((batch << 11) + kk + 16 * ct + c) * DO;
      bf16x8 kf0 = *(const bf16x8*)(Krow + 8 * g);
      bf16x8 kf1 = *(const bf16x8*)(Krow + 32 + 8 * g);
      f32x4 z = {0, 0, 0, 0};
      z = __builtin_amdgcn_mfma_f32_16x16x32_bf16(qf0, kf0, z, 0, 0, 0);
      z = __builtin_amdgcn_mfma_f32_16x16x32_bf16(qf1, kf1, z, 0, 0, 0);
      s[ct] = z;
    }
    // scale + causal mask (always applied; cheap & covers partial tiles)
#pragma unroll
    for (int ct = 0; ct < 4; ++ct) {
      int col = kk + 16 * ct + c;
#pragma unroll
      for (int r = 0; r < 4; ++r) {
        float vv = s[ct][r] * 0.125f;
        if (col > qb + 4 * g + r) vv = -1e30f;
        s[ct][r] = vv;
      }
    }
    // online softmax, rows 4g+r; reduce across the 16 lanes of the g-group
#pragma unroll
    for (int r = 0; r < 4; ++r) {
      float rm = fmaxf(fmaxf(s[0][r], s[1][r]), fmaxf(s[2][r], s[3][r]));
      rm = fmaxf(rm, __shfl_xor(rm, 1));
      rm = fmaxf(rm, __shfl_xor(rm, 2));
      rm = fmaxf(rm, __shfl_xor(rm, 4));
      rm = fmaxf(rm, __shfl_xor(rm, 8));
      float mnew = fmaxf(mr[r], rm);
      float sf = __expf(mr[r] - mnew);
      mr[r] = mnew;
      float rs = 0.f;
#pragma unroll
      for (int ct = 0; ct < 4; ++ct) {
        float p = __expf(s[ct][r] - mnew);
        s[ct][r] = p;
        rs += p;
      }
      rs += __shfl_xor(rs, 1);
      rs += __shfl_xor(rs, 2);
      rs += __shfl_xor(rs, 4);
      rs += __shfl_xor(rs, 8);
      lr[r] = lr[r] * sf + rs;
#pragma unroll
      for (int dt = 0; dt < 4; ++dt) acc[dt][r] *= sf;
    }
    // P -> LDS (re-layout C-frag -> A-frag). [16][72] pad keeps b128 reads ~conflict-free.
#pragma unroll
    for (int ct = 0; ct < 4; ++ct)
#pragma unroll
      for (int r = 0; r < 4; ++r)
        P[4 * g + r][16 * ct + c] = f2bf(s[ct][r]);
    // PV: acc[dt] += P(16x64) @ V(64x16dt)
#pragma unroll
    for (int ks = 0; ks < 2; ++ks) {
      bf16x8 pf = *(const bf16x8*)&P[c][32 * ks + 8 * g];
#pragma unroll
      for (int dt = 0; dt < 4; ++dt) {
        const short* Vr = Vt + (size_t)(batch * 64 + 16 * dt + c) * SQ + kk + 32 * ks + 8 * g;
        bf16x8 vf = *(const bf16x8*)Vr;
        acc[dt] = __builtin_amdgcn_mfma_f32_16x16x32_bf16(pf, vf, acc[dt], 0, 0, 0);
      }
    }
  }
  // store partial
  float* Pb = Po + ((size_t)((batch * 128 + t) * 4 + slot) << 10);
#pragma unroll
  for (int dt = 0; dt < 4; ++dt)
#pragma unroll
    for (int r = 0; r < 4; ++r)
      Pb[(4 * g + r) * 64 + 16 * dt + c] = acc[dt][r];
  if (c == 0) {
    float* Mb = Pml + ((size_t)((batch * 128 + t) * 4 + slot) << 5);
#pragma unroll
    for (int r = 0; r < 4; ++r) {
      Mb[(4 * g + r) * 2]     = mr[r];
      Mb[(4 * g + r) * 2 + 1] = lr[r];
    }
  }
}

// Task map (per batch, 260 tasks):
//  tau<196  : full 512-k chunks: ch0 t=31..127 (97), ch1 t=63..127 (65), ch2 t=95..127 (33), ch3 t=127 (1)
//  tau>=196 : paired partial chunks: u=tau-196, base=(u>>4)*32, j=u&15 -> t1=base+j, t2=base+30-j
__global__ __launch_bounds__(256) void k_attn(const short* __restrict__ Qp,
                                              const short* __restrict__ Kp,
                                              const short* __restrict__ Vt,
                                              float* __restrict__ Po,
                                              float* __restrict__ Pml) {
  __shared__ __align__(16) short Plds[4][16][72];
  int tid = threadIdx.x;
  int w = tid >> 6, lane = tid & 63, g = lane >> 4, c = lane & 15;
  short (*P)[72] = Plds[w];
  int task = blockIdx.x * 4 + w;                     // 0..2079
  int batch = task / 260;
  int tau = task - batch * 260;
  int tA, k0A, keA, slA;
  int tB = -1, k0B = 0, keB = 0, slB = 0;
  if (tau < 196) {
    int ch, t;
    if (tau < 97)       { ch = 0; t = 31 + tau; }
    else if (tau < 162) { ch = 1; t = 63 + (tau - 97); }
    else if (tau < 195) { ch = 2; t = 95 + (tau - 162); }
    else                { ch = 3; t = 127; }
    tA = t; k0A = 512 * ch; keA = 512 * (ch + 1); slA = ch;
  } else {
    int u = tau - 196;
    int base = (u >> 4) * 32, j = u & 15;
    int t1 = base + j, t2 = base + 30 - j;
    tA = t1; k0A = 512 * (t1 >> 5); keA = 16 * t1 + 16; slA = t1 >> 5;
    if (t2 != t1) { tB = t2; k0B = 512 * (t2 >> 5); keB = 16 * t2 + 16; slB = t2 >> 5; }
  }
  attn_task(batch, tA, k0A, keA, slA, g, c, P, Qp, Kp, Vt, Po, Pml);
  if (tB >= 0)
    attn_task(batch, tB, k0B, keB, slB, g, c, P, Qp, Kp, Vt, Po, Pml);
}

// ---------------- Combine partials -> output ----------------
__global__ __launch_bounds__(256) void k_combine(const float* __restrict__ Po,
                                                 const float* __restrict__ Pml,
                                                 float* __restrict__ out) {
  int id = blockIdx.x * 256 + threadIdx.x;           // 8*128*16*16 = 262144
  int d4  = id & 15;
  int row = (id >> 4) & 15;
  int t   = (id >> 8) & 127;
  int b   = id >> 15;
  int nch = (t >> 5) + 1;
  size_t base = (size_t)(b * 128 + t) * 4;
  float mv[4], lv[4];
  float m = -1e30f;
  for (int ci = 0; ci < nch; ++ci) {
    const float* ml = Pml + ((base + ci) << 5) + row * 2;
    mv[ci] = ml[0];
    lv[ci] = ml[1];
    m = fmaxf(m, mv[ci]);
  }
  float lsum = 0.f;
  f32x4 o = {0, 0, 0, 0};
  for (int ci = 0; ci < nch; ++ci) {
    float e = __expf(mv[ci] - m);
    lsum += lv[ci] * e;
    f32x4 oc = *(const f32x4*)(Po + ((base + ci) << 10) + row * 64 + d4 * 4);
    o[0] += oc[0] * e; o[1] += oc[1] * e; o[2] += oc[2] * e; o[3] += oc[3] * e;
  }
  float inv = 1.0f / lsum;
  f32x4 res = {o[0] * inv, o[1] * inv, o[2] * inv, o[3] * inv};
  *(f32x4*)(out + (size_t)((b * 2048 + t * 16 + row) * 64) + d4 * 4) = res;
}

extern "C" void kernel_launch(void* const* d_in, const int* in_sizes, int n_in,
                              void* d_out, int out_size, void* d_ws, size_t ws_size,
                              hipStream_t stream) {
  const float* q  = (const float*)d_in[0];
  const float* k  = (const float*)d_in[1];
  const float* v  = (const float*)d_in[2];
  // d_in[3] = mask (int32, analytically tril -> causal hardcoded)
  const float* Wq = (const float*)d_in[4];
  const float* bq = (const float*)d_in[5];
  const float* Wk = (const float*)d_in[6];
  const float* bk = (const float*)d_in[7];
  const float* Wv = (const float*)d_in[8];
  const float* bv = (const float*)d_in[9];

  char* ws = (char*)d_ws;
  short* Wt  = (short*)(ws);                         // 3*64*1024*2      =   393216
  short* Qp  = (short*)(ws + 393216);                // 16384*64*2       =  2097152
  short* Kp  = (short*)(ws + 2490368);               // 16384*64*2
  short* Vt  = (short*)(ws + 4587520);               // 8*64*2048*2
  float* Po  = (float*)(ws + 6684672);               // 8*128*4*16*64*4  = 16777216
  float* Pml = (float*)(ws + 23461888);              // 8*128*4*16*2*4   =   524288
  float* out = (float*)d_out;

  hipLaunchKernelGGL(k_wconv,   dim3(768),  dim3(256), 0, stream, Wq, Wk, Wv, Wt);
  hipLaunchKernelGGL(k_proj,    dim3(768),  dim3(256), 0, stream, q, k, v, bq, bk, bv, Wt, Qp, Kp, Vt);
  hipLaunchKernelGGL(k_attn,    dim3(520),  dim3(256), 0, stream, Qp, Kp, Vt, Po, Pml);
  hipLaunchKernelGGL(k_combine, dim3(1024), dim3(256), 0, stream, Po, Pml, out);
}

// Round 2
// 289.195 us; speedup vs baseline: 1.0181x; 1.0181x over previous
//
#include <hip/hip_runtime.h>

// SelfAttention: B=8, S=2048, D_MODEL=1024, D_OUT=64, causal, single head.
//  k_wconv  : W[1024][64] f32 -> Wt[64][1024] bf16 (x3) via LDS transpose (coalesced both sides).
//  k_proj   : X[16384][1024] f32 @ Wt -> Qp/Kp bf16 [16384][64]; V -> Vt bf16 [8][64][2048].
//             2 waves/tile (K split 512+512), depth-4 register prefetch, LDS combine.
//  k_attn   : split-K flash attention, k-chunks of 256, compact triangular task map,
//             4608 wave-tasks (18 waves/CU). V-frags preloaded before softmax chain.
//  k_combine: merge up to 8 partials per qtile with m/l rescale -> f32 out.
// Causal mask hardcoded (input mask is analytically tril). Biases honored.

#define DM 1024
#define DO 64
#define SQ 2048

typedef __attribute__((ext_vector_type(4))) float f32x4;
typedef __attribute__((ext_vector_type(8))) short bf16x8;

__device__ __forceinline__ short f2bf(float x) {
  union { float f; unsigned u; } v; v.f = x;
  unsigned r = v.u + 0x7FFFu + ((v.u >> 16) & 1u);   // RNE
  return (short)(r >> 16);
}

// ---------------- W transpose+convert via LDS: Wt[m][c][k] = W_m[k][c] ----------------
__global__ __launch_bounds__(256) void k_wconv(const float* __restrict__ Wq,
                                               const float* __restrict__ Wk,
                                               const float* __restrict__ Wv,
                                               short* __restrict__ Wt) {
  __shared__ short tile[64][65];
  int bid = blockIdx.x;                              // 48 = 3 matrices x 16 tiles
  int m = bid >> 4, ti = bid & 15;
  const float* W = (m == 0) ? Wq : (m == 1) ? Wk : Wv;
  int tid = threadIdx.x;
#pragma unroll
  for (int i = 0; i < 16; ++i) {
    int lin = tid + 256 * i;                         // 0..4095
    int r = lin >> 6, cc = lin & 63;                 // consecutive tid -> consecutive cc
    tile[r][cc] = f2bf(W[(ti * 64 + r) * 64 + cc]);  // coalesced read
  }
  __syncthreads();
#pragma unroll
  for (int i = 0; i < 16; ++i) {
    int lin = tid + 256 * i;
    int cc = lin >> 6, r = lin & 63;                 // consecutive tid -> consecutive r
    Wt[(m << 16) + cc * DM + ti * 64 + r] = tile[r][cc];  // coalesced write
  }
}

// ---------------- Projections ----------------
// grid 3072: bid>>10 = matrix (0=Q,1=K,2=V), bid&1023 = 16-row tile.
// 2 waves/block: wave w does k in [512w, 512w+512), 16 iters of K=32,
// depth-4 A-prefetch (8 x 16B loads in flight). LDS reduce + epilogue.
__global__ __launch_bounds__(128) void k_proj(const float* __restrict__ q,
                                              const float* __restrict__ k,
                                              const float* __restrict__ v,
                                              const float* __restrict__ bq,
                                              const float* __restrict__ bk,
                                              const float* __restrict__ bv,
                                              const short* __restrict__ Wt,
                                              short* __restrict__ Qp,
                                              short* __restrict__ Kp,
                                              short* __restrict__ Vt) {
  __shared__ float red[2][16][64];
  int bid = blockIdx.x;
  int m = bid >> 10, mt = bid & 1023;
  const float* X    = (m == 0) ? q  : (m == 1) ? k  : v;
  const float* bias = (m == 0) ? bq : (m == 1) ? bk : bv;
  const short* W = Wt + (m << 16);
  int tid = threadIdx.x;
  int w = tid >> 6, lane = tid & 63, g = lane >> 4, c = lane & 15;
  const float* Xrow = X + (size_t)(mt * 16 + c) * DM + (w << 9);
  const short* Wc = W + (w << 9);

  f32x4 pa[4], pb[4];
#pragma unroll
  for (int i = 0; i < 4; ++i) {
    const float* xp = Xrow + 32 * i + 8 * g;
    pa[i] = *(const f32x4*)xp;
    pb[i] = *(const f32x4*)(xp + 4);
  }
  f32x4 acc[4] = {{0,0,0,0},{0,0,0,0},{0,0,0,0},{0,0,0,0}};
#pragma unroll
  for (int i = 0; i < 16; ++i) {
    f32x4 xa = pa[i & 3], xb = pb[i & 3];
    if (i < 12) {                                    // prefetch iter i+4
      const float* xp = Xrow + 32 * (i + 4) + 8 * g;
      pa[i & 3] = *(const f32x4*)xp;
      pb[i & 3] = *(const f32x4*)(xp + 4);
    }
    bf16x8 af;
    af[0] = f2bf(xa[0]); af[1] = f2bf(xa[1]); af[2] = f2bf(xa[2]); af[3] = f2bf(xa[3]);
    af[4] = f2bf(xb[0]); af[5] = f2bf(xb[1]); af[6] = f2bf(xb[2]); af[7] = f2bf(xb[3]);
    int k0 = 32 * i;
#pragma unroll
    for (int ct = 0; ct < 4; ++ct) {
      bf16x8 bfr = *(const bf16x8*)(Wc + (16 * ct + c) * DM + k0 + 8 * g);
      acc[ct] = __builtin_amdgcn_mfma_f32_16x16x32_bf16(af, bfr, acc[ct], 0, 0, 0);
    }
  }
#pragma unroll
  for (int ct = 0; ct < 4; ++ct)
#pragma unroll
    for (int r = 0; r < 4; ++r)
      red[w][4 * g + r][16 * ct + c] = acc[ct][r];
  __syncthreads();

  int row0 = mt * 16;
  if (m < 2) {
    short* dst = (m == 0) ? Qp : Kp;
    int col = tid & 63, rb = (tid >> 6) * 8;
#pragma unroll
    for (int rr = 0; rr < 8; ++rr) {
      int r = rb + rr;
      float vsum = red[0][r][col] + red[1][r][col] + bias[col];
      dst[(size_t)(row0 + r) * DO + col] = f2bf(vsum);
    }
  } else {
    int col = tid >> 1, rb = (tid & 1) * 8;
    int batch = mt >> 7;
    int s0 = ((mt & 127) << 4) + rb;
    float bb = bias[col];
    float vv[8];
#pragma unroll
    for (int rr = 0; rr < 8; ++rr)
      vv[rr] = red[0][rb + rr][col] + red[1][rb + rr][col] + bb;
    ushort4 p0, p1;
    p0.x = (unsigned short)f2bf(vv[0]); p0.y = (unsigned short)f2bf(vv[1]);
    p0.z = (unsigned short)f2bf(vv[2]); p0.w = (unsigned short)f2bf(vv[3]);
    p1.x = (unsigned short)f2bf(vv[4]); p1.y = (unsigned short)f2bf(vv[5]);
    p1.z = (unsigned short)f2bf(vv[6]); p1.w = (unsigned short)f2bf(vv[7]);
    short* Vb = Vt + (size_t)(batch * 64 + col) * SQ + s0;
    *(ushort4*)Vb = p0;
    *(ushort4*)(Vb + 4) = p1;
  }
}

// ---------------- Flash attention (split-K, partials) ----------------
// One wave = one task: qtile t (16 rows), k in [k0, kend), kend-k0 <= 256.
// Writes unnormalized partial O[16][64] + (m,l)[16] at compact task slot.
__device__ __forceinline__ void attn_task(int batch, int t, int k0, int kend,
                                          int g, int c, short (*P)[72],
                                          const short* __restrict__ Qp,
                                          const short* __restrict__ Kp,
                                          const short* __restrict__ Vt,
                                          float* __restrict__ Pb,
                                          float* __restrict__ Mb) {
  const int qb = t * 16;
  const short* Qrow = Qp + (size_t)((batch << 11) + qb + c) * DO;
  bf16x8 qf0 = *(const bf16x8*)(Qrow + 8 * g);
  bf16x8 qf1 = *(const bf16x8*)(Qrow + 32 + 8 * g);
  f32x4 acc[4] = {{0,0,0,0},{0,0,0,0},{0,0,0,0},{0,0,0,0}};
  float mr[4] = {-1e30f, -1e30f, -1e30f, -1e30f};
  float lr[4] = {0.f, 0.f, 0.f, 0.f};
  int nkt = (kend - k0 + 63) >> 6;
  for (int kt = 0; kt < nkt; ++kt) {
    int kk = k0 + (kt << 6);
    // QK^T: S[4g+r][16ct+c]
    f32x4 s[4];
#pragma unroll
    for (int ct = 0; ct < 4; ++ct) {
      const short* Krow = Kp + (size_t)((batch << 11) + kk + 16 * ct + c) * DO;
      bf16x8 kf0 = *(const bf16x8*)(Krow + 8 * g);
      bf16x8 kf1 = *(const bf16x8*)(Krow + 32 + 8 * g);
      f32x4 z = {0, 0, 0, 0};
      z = __builtin_amdgcn_mfma_f32_16x16x32_bf16(qf0, kf0, z, 0, 0, 0);
      z = __builtin_amdgcn_mfma_f32_16x16x32_bf16(qf1, kf1, z, 0, 0, 0);
      s[ct] = z;
    }
    // Preload all 8 V-frags now; softmax VALU chain below hides the L2 latency.
    bf16x8 vf[8];
#pragma unroll
    for (int ks = 0; ks < 2; ++ks)
#pragma unroll
      for (int dt = 0; dt < 4; ++dt)
        vf[ks * 4 + dt] = *(const bf16x8*)(Vt + (size_t)(batch * 64 + 16 * dt + c) * SQ
                                           + kk + 32 * ks + 8 * g);
    // scale + causal mask
#pragma unroll
    for (int ct = 0; ct < 4; ++ct) {
      int col = kk + 16 * ct + c;
#pragma unroll
      for (int r = 0; r < 4; ++r) {
        float vv = s[ct][r] * 0.125f;
        if (col > qb + 4 * g + r) vv = -1e30f;
        s[ct][r] = vv;
      }
    }
    // online softmax, rows 4g+r; reduce across the 16 lanes of the g-group
#pragma unroll
    for (int r = 0; r < 4; ++r) {
      float rm = fmaxf(fmaxf(s[0][r], s[1][r]), fmaxf(s[2][r], s[3][r]));
      rm = fmaxf(rm, __shfl_xor(rm, 1));
      rm = fmaxf(rm, __shfl_xor(rm, 2));
      rm = fmaxf(rm, __shfl_xor(rm, 4));
      rm = fmaxf(rm, __shfl_xor(rm, 8));
      float mnew = fmaxf(mr[r], rm);
      float sf = __expf(mr[r] - mnew);
      mr[r] = mnew;
      float rs = 0.f;
#pragma unroll
      for (int ct = 0; ct < 4; ++ct) {
        float p = __expf(s[ct][r] - mnew);
        s[ct][r] = p;
        rs += p;
      }
      rs += __shfl_xor(rs, 1);
      rs += __shfl_xor(rs, 2);
      rs += __shfl_xor(rs, 4);
      rs += __shfl_xor(rs, 8);
      lr[r] = lr[r] * sf + rs;
#pragma unroll
      for (int dt = 0; dt < 4; ++dt) acc[dt][r] *= sf;
    }
    // P -> LDS (C-frag -> A-frag re-layout), wave-private buffer.
#pragma unroll
    for (int ct = 0; ct < 4; ++ct)
#pragma unroll
      for (int r = 0; r < 4; ++r)
        P[4 * g + r][16 * ct + c] = f2bf(s[ct][r]);
    // PV: acc[dt] += P(16x64) @ V(64x16dt)
#pragma unroll
    for (int ks = 0; ks < 2; ++ks) {
      bf16x8 pf = *(const bf16x8*)&P[c][32 * ks + 8 * g];
#pragma unroll
      for (int dt = 0; dt < 4; ++dt)
        acc[dt] = __builtin_amdgcn_mfma_f32_16x16x32_bf16(pf, vf[ks * 4 + dt], acc[dt], 0, 0, 0);
    }
  }
  // store partial
#pragma unroll
  for (int dt = 0; dt < 4; ++dt)
#pragma unroll
    for (int r = 0; r < 4; ++r)
      Pb[(4 * g + r) * 64 + 16 * dt + c] = acc[dt][r];
  if (c == 0) {
#pragma unroll
    for (int r = 0; r < 4; ++r) {
      Mb[(4 * g + r) * 2]     = mr[r];
      Mb[(4 * g + r) * 2 + 1] = lr[r];
    }
  }
}

// Compact triangular task map, per batch 576 tasks:
// t = 16o + j (o=0..7, j=0..15), chunks ch=0..o of k in [256ch, min(256ch+256,16t+16)).
// idx = 8o(o+1) + j(o+1) + ch.
__global__ __launch_bounds__(256) void k_attn(const short* __restrict__ Qp,
                                              const short* __restrict__ Kp,
                                              const short* __restrict__ Vt,
                                              float* __restrict__ Po,
                                              float* __restrict__ Pml) {
  __shared__ __align__(16) short Plds[4][16][72];
  int tid = threadIdx.x;
  int w = tid >> 6, lane = tid & 63, g = lane >> 4, c = lane & 15;
  int task = blockIdx.x * 4 + w;                     // 0..4607
  int batch = task / 576;
  int idx = task - batch * 576;
  int o = (int)((sqrtf(1.0f + 0.5f * (float)idx) - 1.0f) * 0.5f);
  while (8 * (o + 1) * (o + 2) <= idx) ++o;
  while (8 * o * (o + 1) > idx) --o;
  int rem = idx - 8 * o * (o + 1);
  int j = rem / (o + 1);
  int ch = rem - j * (o + 1);
  int t = 16 * o + j;
  int k0 = ch << 8;
  int kend = min(k0 + 256, 16 * t + 16);
  float* Pb = Po + ((size_t)task << 10);
  float* Mb = Pml + ((size_t)task << 5);
  attn_task(batch, t, k0, kend, g, c, Plds[w], Qp, Kp, Vt, Pb, Mb);
}

// ---------------- Combine partials -> output ----------------
__global__ __launch_bounds__(256) void k_combine(const float* __restrict__ Po,
                                                 const float* __restrict__ Pml,
                                                 float* __restrict__ out) {
  int id = blockIdx.x * 256 + threadIdx.x;           // 8*128*16*16 = 262144
  int d4  = id & 15;
  int row = (id >> 4) & 15;
  int t   = (id >> 8) & 127;
  int b   = id >> 15;
  int o = t >> 4, j = t & 15;
  int nch = o + 1;
  size_t sbase = (size_t)b * 576 + 8 * o * (o + 1) + j * (o + 1);
  float m = -1e30f;
  for (int ci = 0; ci < nch; ++ci)
    m = fmaxf(m, Pml[((sbase + ci) << 5) + row * 2]);
  float lsum = 0.f;
  f32x4 oacc = {0, 0, 0, 0};
  for (int ci = 0; ci < nch; ++ci) {
    const float* ml = Pml + ((sbase + ci) << 5) + row * 2;
    float e = __expf(ml[0] - m);
    lsum += ml[1] * e;
    f32x4 oc = *(const f32x4*)(Po + ((sbase + ci) << 10) + row * 64 + d4 * 4);
    oacc[0] += oc[0] * e; oacc[1] += oc[1] * e;
    oacc[2] += oc[2] * e; oacc[3] += oc[3] * e;
  }
  float inv = 1.0f / lsum;
  f32x4 res = {oacc[0] * inv, oacc[1] * inv, oacc[2] * inv, oacc[3] * inv};
  *(f32x4*)(out + (size_t)((b << 11) + (t << 4) + row) * 64 + d4 * 4) = res;
}

extern "C" void kernel_launch(void* const* d_in, const int* in_sizes, int n_in,
                              void* d_out, int out_size, void* d_ws, size_t ws_size,
                              hipStream_t stream) {
  const float* q  = (const float*)d_in[0];
  const float* k  = (const float*)d_in[1];
  const float* v  = (const float*)d_in[2];
  // d_in[3] = mask (int32, analytically tril -> causal hardcoded)
  const float* Wq = (const float*)d_in[4];
  const float* bq = (const float*)d_in[5];
  const float* Wk = (const float*)d_in[6];
  const float* bk = (const float*)d_in[7];
  const float* Wv = (const float*)d_in[8];
  const float* bv = (const float*)d_in[9];

  char* ws = (char*)d_ws;
  short* Wt  = (short*)(ws);                         // 3*64*1024*2      =   393216
  short* Qp  = (short*)(ws + 393216);                // 16384*64*2      =  2097152
  short* Kp  = (short*)(ws + 2490368);               // 16384*64*2
  short* Vt  = (short*)(ws + 4587520);               // 8*64*2048*2
  float* Po  = (float*)(ws + 6684672);               // 4608*16*64*4    = 18874368
  float* Pml = (float*)(ws + 25559040);              // 4608*32*4       =   589824
  float* out = (float*)d_out;                        // end: 26148864

  hipLaunchKernelGGL(k_wconv,   dim3(48),   dim3(256), 0, stream, Wq, Wk, Wv, Wt);
  hipLaunchKernelGGL(k_proj,    dim3(3072), dim3(128), 0, stream, q, k, v, bq, bk, bv, Wt, Qp, Kp, Vt);
  hipLaunchKernelGGL(k_attn,    dim3(1152), dim3(256), 0, stream, Qp, Kp, Vt, Po, Pml);
  hipLaunchKernelGGL(k_combine, dim3(1024), dim3(256), 0, stream, Po, Pml, out);
}